// Round 4
// baseline (218.295 us; speedup 1.0000x reference)
//
#include <hip/hip_runtime.h>
#include <hip/hip_bf16.h>

typedef unsigned int u32;
typedef unsigned short u16;
typedef __attribute__((ext_vector_type(8))) short bf16x8;   // 8 x bf16 (4 VGPR)
typedef __attribute__((ext_vector_type(4))) short bf16x4;   // 4 x bf16 (2 VGPR)
typedef __attribute__((ext_vector_type(4))) float f32x4;
typedef __attribute__((ext_vector_type(2))) u32 u32x2;

#define LOG2E 1.4426950408889634f
#define SCALE 0.17677669529663687f   /* 32^-0.5 */

__device__ __forceinline__ u16 f2bf(float f) {
    return __builtin_bit_cast(u16, __float2bfloat16(f));    // native cvt, RNE
}
__device__ __forceinline__ u32 pkbf(float a, float b) {
    return (u32)f2bf(a) | ((u32)f2bf(b) << 16);
}
__device__ __forceinline__ bf16x4 pk4(f32x4 v) {
    u32x2 p; p.x = pkbf(v[0], v[1]); p.y = pkbf(v[2], v[3]);
    return __builtin_bit_cast(bf16x4, p);
}

// K=16 bf16 MFMA: A/B frag = lane(g,c): [row c][k 4g..4g+3]; D as usual.
#if __has_builtin(__builtin_amdgcn_mfma_f32_16x16x16bf16_1k)
#define MFMA16(A, B, C) __builtin_amdgcn_mfma_f32_16x16x16bf16_1k((A), (B), (C), 0, 0, 0)
#else
__device__ __forceinline__ f32x4 mfma16_fb(bf16x4 a, bf16x4 b, f32x4 c) {
    bf16x8 a8 = {a[0], a[1], a[2], a[3], 0, 0, 0, 0};
    bf16x8 b8 = {b[0], b[1], b[2], b[3], 0, 0, 0, 0};
    return __builtin_amdgcn_mfma_f32_16x16x32_bf16(a8, b8, c, 0, 0, 0);
}
#define MFMA16(A, B, C) mfma16_fb((A), (B), (C))
#endif

// XOR-swizzled element index for [rows][128] / [rows][64] bf16 LDS tiles
__device__ __forceinline__ int sw128(int r, int e) { return r * 128 + (e ^ ((r & 7) << 3)); }
__device__ __forceinline__ int sw64 (int r, int e) { return r * 64  + (e ^ ((r & 7) << 3)); }

__global__ __launch_bounds__(256) void prep_kernel(
    const float* __restrict__ Wq, const float* __restrict__ Wk,
    const float* __restrict__ Wv, const float* __restrict__ Wo,
    const float* __restrict__ bias_table, const int* __restrict__ rel_index,
    u16* __restrict__ wsW, float* __restrict__ wsB)
{
    int idx = blockIdx.x * 256 + threadIdx.x;
    if (idx < 16384) {
        wsW[idx]         = f2bf(Wq[idx] * (SCALE * LOG2E));  // fold scale*log2e into Wq
        wsW[16384 + idx] = f2bf(Wk[idx]);
        wsW[32768 + idx] = f2bf(Wv[idx]);
        wsW[49152 + idx] = f2bf(Wo[idx]);
        // bias laid out so the QK^T MFMA C-init is one dwordx4 per lane:
        // wsB[(((h*4+mt)*4+nt)*64 + lane)*4 + r] = bias[h][kk=16mt+4g+r][q=16nt+c] * LOG2E
        int h = idx >> 12, t = (idx >> 8) & 15, l = (idx >> 2) & 63, r = idx & 3;
        int mt = t >> 2, nt = t & 3, g = l >> 4, c = l & 15;
        int kk = 16 * mt + 4 * g + r, q = 16 * nt + c;
        wsB[idx] = bias_table[rel_index[q * 64 + kk] * 4 + h] * LOG2E;
    }
}

// LDS (32 KB): Xs = x tile 64x128 bf16 (later hc); vT per-wave 32x64 at 8192 + wid*2048
__global__ __launch_bounds__(256, 4) void wattn_kernel(
    const float* __restrict__ x,
    const float* __restrict__ bq, const float* __restrict__ bk,
    const float* __restrict__ bv, const float* __restrict__ bo,
    const u16* __restrict__ Wbf, const float* __restrict__ biasT,
    float* __restrict__ out)
{
    __shared__ u16 smem[16384];

    const int b    = blockIdx.x;
    const int tid  = threadIdx.x;
    const int wid  = tid >> 6;
    const int lane = tid & 63;
    const int g    = lane >> 4;
    const int c    = lane & 15;
    const int h    = wid;

    u16* Xs = smem;                       // x tile; later hc
    u16* vT = smem + 8192 + wid * 2048;   // per-wave V^T [ch within head][tok]

    // ---- stage x -> LDS bf16 (coalesced float4) ----
    {
        const float* xb = x + (size_t)b * 8192;
        #pragma unroll
        for (int it = 0; it < 8; ++it) {
            int idx = it * 1024 + tid * 4;
            float4 v = *(const float4*)(xb + idx);
            int row = idx >> 7, col = idx & 127;
            u32x2 wv;
            wv.x = pkbf(v.x, v.y);
            wv.y = pkbf(v.z, v.w);
            *(u32x2*)&Xs[sw128(row, col)] = wv;
        }
    }
    __syncthreads();

    // ---- x tile fragments hoisted ONCE (A/B frag layouts identical for 16x16x32) ----
    bf16x8 xa[4][4];
    #pragma unroll
    for (int mt = 0; mt < 4; ++mt)
        #pragma unroll
        for (int kt = 0; kt < 4; ++kt)
            xa[mt][kt] = *(const bf16x8*)&Xs[sw128(16 * mt + c, 32 * kt + 8 * g)];

    // ---- phase A: q,k output-transposed D[ch][tok] into registers ----
    bf16x4 qpk[4][2], kpk[4][2];
    #pragma unroll
    for (int p = 0; p < 2; ++p) {
        const float* bp = (p == 0) ? bq : bk;
        const u16* W = Wbf + p * 16384;
        float bscale = (p == 0) ? (SCALE * LOG2E) : 1.0f;
        f32x4 acc[2][4];
        #pragma unroll
        for (int CT = 0; CT < 2; ++CT) {
            float4 bb = *(const float4*)&bp[32 * h + 16 * CT + 4 * g];
            f32x4 bi = {bb.x * bscale, bb.y * bscale, bb.z * bscale, bb.w * bscale};
            #pragma unroll
            for (int nt = 0; nt < 4; ++nt) acc[CT][nt] = bi;
        }
        #pragma unroll
        for (int kt = 0; kt < 4; ++kt)
            #pragma unroll
            for (int CT = 0; CT < 2; ++CT) {
                bf16x8 wf = *(const bf16x8*)(W + (32 * h + 16 * CT + c) * 128 + 32 * kt + 8 * g);
                #pragma unroll
                for (int nt = 0; nt < 4; ++nt)
                    acc[CT][nt] = __builtin_amdgcn_mfma_f32_16x16x32_bf16(wf, xa[nt][kt], acc[CT][nt], 0, 0, 0);
            }
        #pragma unroll
        for (int nt = 0; nt < 4; ++nt)
            #pragma unroll
            for (int CT = 0; CT < 2; ++CT) {
                bf16x4 pk = pk4(acc[CT][nt]);
                if (p == 0) qpk[nt][CT] = pk; else kpk[nt][CT] = pk;
            }
    }

    // v: standard orientation D[tok][ch] -> transposed packed store to vT[ch][tok]
    {
        const u16* Wv_ = Wbf + 32768;
        f32x4 acc[2][4];
        #pragma unroll
        for (int j = 0; j < 2; ++j) {
            float bcol = bv[32 * h + 16 * j + c];
            #pragma unroll
            for (int mt = 0; mt < 4; ++mt) { f32x4 t = {bcol, bcol, bcol, bcol}; acc[j][mt] = t; }
        }
        #pragma unroll
        for (int kt = 0; kt < 4; ++kt)
            #pragma unroll
            for (int j = 0; j < 2; ++j) {
                bf16x8 wf = *(const bf16x8*)(Wv_ + (32 * h + 16 * j + c) * 128 + 32 * kt + 8 * g);
                #pragma unroll
                for (int mt = 0; mt < 4; ++mt)
                    acc[j][mt] = __builtin_amdgcn_mfma_f32_16x16x32_bf16(xa[mt][kt], wf, acc[j][mt], 0, 0, 0);
            }
        #pragma unroll
        for (int j = 0; j < 2; ++j)
            #pragma unroll
            for (int mt = 0; mt < 4; ++mt) {
                u32x2 wv;
                wv.x = pkbf(acc[j][mt][0], acc[j][mt][1]);
                wv.y = pkbf(acc[j][mt][2], acc[j][mt][3]);
                *(u32x2*)&vT[sw64(16 * j + c, 16 * mt + 4 * g)] = wv;
            }
    }

    // ---- QK^T (all-register): S^T[kk][q], bias C-init loaded straight into acc ----
    f32x4 accS[4][4];
    {
        const f32x4* bT = (const f32x4*)(biasT + h * 4096);
        #pragma unroll
        for (int mt = 0; mt < 4; ++mt)
            #pragma unroll
            for (int nt = 0; nt < 4; ++nt)
                accS[mt][nt] = bT[(mt * 4 + nt) * 64 + lane];
        #pragma unroll
        for (int mt = 0; mt < 4; ++mt)
            #pragma unroll
            for (int nt = 0; nt < 4; ++nt) {
                accS[mt][nt] = MFMA16(kpk[mt][0], qpk[nt][0], accS[mt][nt]);
                accS[mt][nt] = MFMA16(kpk[mt][1], qpk[nt][1], accS[mt][nt]);
            }
    }

    // ---- softmax over kk (rows of S^T); 1/sum deferred to post-PV rescale ----
    float rinv[4];
    #pragma unroll
    for (int nt = 0; nt < 4; ++nt) {
        float m = accS[0][nt][0];
        #pragma unroll
        for (int mt = 0; mt < 4; ++mt)
            #pragma unroll
            for (int r = 0; r < 4; ++r) m = fmaxf(m, accS[mt][nt][r]);
        m = fmaxf(m, __shfl_xor(m, 16, 64));
        m = fmaxf(m, __shfl_xor(m, 32, 64));
        float s = 0.f;
        #pragma unroll
        for (int mt = 0; mt < 4; ++mt)
            #pragma unroll
            for (int r = 0; r < 4; ++r) {
                float e = exp2f(accS[mt][nt][r] - m);
                accS[mt][nt][r] = e;
                s += e;
            }
        s += __shfl_xor(s, 16, 64);
        s += __shfl_xor(s, 32, 64);
        rinv[nt] = 1.0f / s;
    }

    // ---- P stays in-register: pack accS -> K=16 A-frags ----
    bf16x4 ppk[4][4];
    #pragma unroll
    for (int mt = 0; mt < 4; ++mt)
        #pragma unroll
        for (int nt = 0; nt < 4; ++nt) ppk[mt][nt] = pk4(accS[mt][nt]);

    // ---- PV: outT[ch][tok] = V^T . P ----
    f32x4 accO[2][4];
    #pragma unroll
    for (int mD = 0; mD < 2; ++mD)
        #pragma unroll
        for (int nt = 0; nt < 4; ++nt) { f32x4 z = {0.f, 0.f, 0.f, 0.f}; accO[mD][nt] = z; }
    #pragma unroll
    for (int mD = 0; mD < 2; ++mD) {
        bf16x4 vf[4];
        #pragma unroll
        for (int mt = 0; mt < 4; ++mt)
            vf[mt] = *(const bf16x4*)&vT[sw64(16 * mD + c, 16 * mt + 4 * g)];
        #pragma unroll
        for (int nt = 0; nt < 4; ++nt)
            #pragma unroll
            for (int mt = 0; mt < 4; ++mt)
                accO[mD][nt] = MFMA16(vf[mt], ppk[mt][nt], accO[mD][nt]);
    }
    __syncthreads();   // everyone done reading Xs/vT -> Xs reusable for hc

    // head output (rescaled) -> hc[tok][ch], 4 consecutive channels per lane = b64 store
    #pragma unroll
    for (int mD = 0; mD < 2; ++mD)
        #pragma unroll
        for (int nt = 0; nt < 4; ++nt) {
            float riv = rinv[nt];
            u32x2 wv;
            wv.x = pkbf(accO[mD][nt][0] * riv, accO[mD][nt][1] * riv);
            wv.y = pkbf(accO[mD][nt][2] * riv, accO[mD][nt][3] * riv);
            *(u32x2*)&Xs[sw128(16 * nt + c, 32 * h + 16 * mD + 4 * g)] = wv;
        }
    __syncthreads();

    // ---- phase C: out^T orientation (A=Wo, B=hc). Compute BOTH och-halves first,
    //      then store each 128-B output line as two back-to-back 64-B halves. ----
    bf16x8 ha[4][4];
    #pragma unroll
    for (int nt = 0; nt < 4; ++nt)
        #pragma unroll
        for (int kt = 0; kt < 4; ++kt)
            ha[nt][kt] = *(const bf16x8*)&Xs[sw128(16 * nt + c, 32 * kt + 8 * g)];
    const u16* Wo_ = Wbf + 49152;
    float* ob = out + (size_t)b * 8192;
    f32x4 acc2[2][4];
    #pragma unroll
    for (int j = 0; j < 2; ++j) {
        int OT = 2 * wid + j;
        float4 bb = *(const float4*)&bo[16 * OT + 4 * g];
        #pragma unroll
        for (int nt = 0; nt < 4; ++nt) { f32x4 t = {bb.x, bb.y, bb.z, bb.w}; acc2[j][nt] = t; }
        #pragma unroll
        for (int kt = 0; kt < 4; ++kt) {
            bf16x8 wof = *(const bf16x8*)(Wo_ + (16 * OT + c) * 128 + 32 * kt + 8 * g);
            #pragma unroll
            for (int nt = 0; nt < 4; ++nt)
                acc2[j][nt] = __builtin_amdgcn_mfma_f32_16x16x32_bf16(wof, ha[nt][kt], acc2[j][nt], 0, 0, 0);
        }
    }
    #pragma unroll
    for (int nt = 0; nt < 4; ++nt)
        #pragma unroll
        for (int j = 0; j < 2; ++j)   // adjacent stores cover both 64-B halves of each line
            *(f32x4*)&ob[(16 * nt + c) * 128 + 16 * (2 * wid + j) + 4 * g] = acc2[j][nt];
}

extern "C" void kernel_launch(void* const* d_in, const int* in_sizes, int n_in,
                              void* d_out, int out_size, void* d_ws, size_t ws_size,
                              hipStream_t stream)
{
    const float* query      = (const float*)d_in[0];
    const float* Wq         = (const float*)d_in[1];
    const float* bq         = (const float*)d_in[2];
    const float* Wk         = (const float*)d_in[3];
    const float* bk         = (const float*)d_in[4];
    const float* Wv         = (const float*)d_in[5];
    const float* bv         = (const float*)d_in[6];
    const float* Wo         = (const float*)d_in[7];
    const float* bo         = (const float*)d_in[8];
    const float* bias_table = (const float*)d_in[9];
    const int*   rel_index  = (const int*)d_in[10];

    u16*   wsW = (u16*)d_ws;                          // 4 x 32 KB bf16 weights
    float* wsB = (float*)((char*)d_ws + 131072);      // bias, MFMA-C-init layout, 64 KB

    prep_kernel<<<dim3(64), dim3(256), 0, stream>>>(Wq, Wk, Wv, Wo, bias_table, rel_index, wsW, wsB);
    wattn_kernel<<<dim3(4096), dim3(256), 0, stream>>>(query, bq, bk, bv, bo, wsW, wsB, (float*)d_out);
}

// Round 5
// 126.791 us; speedup vs baseline: 1.7217x; 1.7217x over previous
//
#include <hip/hip_runtime.h>
#include <hip/hip_bf16.h>

typedef unsigned int u32;
typedef unsigned short u16;
typedef __attribute__((ext_vector_type(8))) short bf16x8;   // 8 x bf16 (4 VGPR)
typedef __attribute__((ext_vector_type(4))) float f32x4;
typedef __attribute__((ext_vector_type(2))) u32 u32x2;

#define LOG2E 1.4426950408889634f
#define SCALE 0.17677669529663687f   /* 32^-0.5 */

__device__ __forceinline__ u16 f2bf(float f) {
    return __builtin_bit_cast(u16, __float2bfloat16(f));    // native cvt, RNE
}
__device__ __forceinline__ u32 pkbf(float a, float b) {
    return (u32)f2bf(a) | ((u32)f2bf(b) << 16);
}

// XOR-swizzled element index for [rows][128] / [rows][64] bf16 LDS tiles
__device__ __forceinline__ int sw128(int r, int e) { return r * 128 + (e ^ ((r & 7) << 3)); }
__device__ __forceinline__ int sw64 (int r, int e) { return r * 64  + (e ^ ((r & 7) << 3)); }

__global__ __launch_bounds__(256) void prep_kernel(
    const float* __restrict__ Wq, const float* __restrict__ Wk,
    const float* __restrict__ Wv, const float* __restrict__ Wo,
    const float* __restrict__ bias_table, const int* __restrict__ rel_index,
    u16* __restrict__ wsW, float* __restrict__ wsB)
{
    int idx = blockIdx.x * 256 + threadIdx.x;
    if (idx < 16384) {
        wsW[idx]         = f2bf(Wq[idx] * (SCALE * LOG2E));  // fold scale*log2e into Wq
        wsW[16384 + idx] = f2bf(Wk[idx]);
        wsW[32768 + idx] = f2bf(Wv[idx]);
        wsW[49152 + idx] = f2bf(Wo[idx]);
        // bias laid out so the QK^T MFMA C-init is one dwordx4 per lane:
        // wsB[(((h*4+mt)*4+nt)*64 + lane)*4 + r] = bias[h][kk=16mt+4g+r][q=16nt+c] * LOG2E
        int h = idx >> 12, t = (idx >> 8) & 15, l = (idx >> 2) & 63, r = idx & 3;
        int mt = t >> 2, nt = t & 3, g = l >> 4, c = l & 15;
        int kk = 16 * mt + 4 * g + r, q = 16 * nt + c;
        wsB[idx] = bias_table[rel_index[q * 64 + kk] * 4 + h] * LOG2E;
    }
}

// LDS (48 KB total):
//   smem[0..8191]        : x tile 64x128 bf16 (dead after xa hoist); later hc 64x128
//   per-wave w at w*6144 : qk 64x64 (q cols 0..31, k cols 32..63); later P 64x64
//                          vT 32x64 [chan][tok] at +4096
__global__ __launch_bounds__(256, 3) void wattn_kernel(
    const float* __restrict__ x,
    const float* __restrict__ bq, const float* __restrict__ bk,
    const float* __restrict__ bv, const float* __restrict__ bo,
    const u16* __restrict__ Wbf, const float* __restrict__ biasT,
    float* __restrict__ out)
{
    __shared__ u16 smem[24576];   // 48 KB -> 3 blocks/CU

    const int b    = blockIdx.x;
    const int tid  = threadIdx.x;
    const int wid  = tid >> 6;
    const int lane = tid & 63;
    const int g    = lane >> 4;
    const int c    = lane & 15;
    const int h    = wid;

    u16* Xs = smem;                // x tile; later hc
    u16* qk = smem + wid * 6144;   // per-wave q|k buffer; later P
    u16* vT = qk + 4096;           // per-wave V^T [ch within head][tok]

    // ---- stage x -> LDS bf16 (coalesced float4) ----
    {
        const float* xb = x + (size_t)b * 8192;
        #pragma unroll
        for (int it = 0; it < 8; ++it) {
            int idx = it * 1024 + tid * 4;
            float4 v = *(const float4*)(xb + idx);
            int row = idx >> 7, col = idx & 127;
            u32x2 wv;
            wv.x = pkbf(v.x, v.y);
            wv.y = pkbf(v.z, v.w);
            *(u32x2*)&Xs[sw128(row, col)] = wv;
        }
    }
    __syncthreads();

    // ---- whole x tile as A-frags in registers (16 VGPR x 4 = 64) ----
    bf16x8 xa[4][4];
    #pragma unroll
    for (int mt = 0; mt < 4; ++mt)
        #pragma unroll
        for (int kt = 0; kt < 4; ++kt)
            xa[mt][kt] = *(const bf16x8*)&Xs[sw128(16 * mt + c, 32 * kt + 8 * g)];
    __syncthreads();   // x region now reusable as wave buffers

    // ---- phase A: this wave's OWN head q/k/v (wave-local from here to PV) ----
    #pragma unroll
    for (int p = 0; p < 3; ++p) {
        const float* bp = (p == 0) ? bq : (p == 1) ? bk : bv;
        #pragma unroll
        for (int j = 0; j < 2; ++j) {
            int nt = 2 * h + j;
            float bcol = bp[16 * nt + c];
            if (p == 0) bcol *= (SCALE * LOG2E);
            f32x4 acc[4];
            #pragma unroll
            for (int mt = 0; mt < 4; ++mt) { f32x4 t = {bcol, bcol, bcol, bcol}; acc[mt] = t; }
            const u16* W = Wbf + p * 16384 + (16 * nt + c) * 128;
            #pragma unroll
            for (int kt = 0; kt < 4; ++kt) {
                bf16x8 bfr = *(const bf16x8*)(W + 32 * kt + 8 * g);
                #pragma unroll
                for (int mt = 0; mt < 4; ++mt)
                    acc[mt] = __builtin_amdgcn_mfma_f32_16x16x32_bf16(xa[mt][kt], bfr, acc[mt], 0, 0, 0);
            }
            if (p < 2) {               // q at cols 0..31, k at cols 32..63 (within-head channel)
                int colb = p * 32 + 16 * j + c;
                #pragma unroll
                for (int mt = 0; mt < 4; ++mt)
                    #pragma unroll
                    for (int r = 0; r < 4; ++r)
                        qk[sw64(16 * mt + 4 * g + r, colb)] = f2bf(acc[mt][r]);
            } else {                   // v transposed: [chan within head][tok], packed 8B stores
                #pragma unroll
                for (int mt = 0; mt < 4; ++mt) {
                    u32x2 wv;
                    wv.x = pkbf(acc[mt][0], acc[mt][1]);
                    wv.y = pkbf(acc[mt][2], acc[mt][3]);
                    *(u32x2*)&vT[sw64(16 * j + c, 16 * mt + 4 * g)] = wv;
                }
            }
        }
    }

    // ---- attention (wave-local, barrier-free): S^T = K.Q^T with bias C-init ----
    bf16x8 ka[4], qb[4];
    #pragma unroll
    for (int t = 0; t < 4; ++t) {
        qb[t] = *(const bf16x8*)&qk[sw64(16 * t + c, 8 * g)];
        ka[t] = *(const bf16x8*)&qk[sw64(16 * t + c, 32 + 8 * g)];
    }
    f32x4 accS[4][4];
    const f32x4* bT = (const f32x4*)(biasT + h * 4096);
    #pragma unroll
    for (int mt = 0; mt < 4; ++mt)
        #pragma unroll
        for (int nt = 0; nt < 4; ++nt)
            accS[mt][nt] = __builtin_amdgcn_mfma_f32_16x16x32_bf16(
                ka[mt], qb[nt], bT[(mt * 4 + nt) * 64 + lane], 0, 0, 0);

    // ---- softmax over kk (rows of S^T); 1/sum deferred to post-PV rescale ----
    float rinv[4];
    #pragma unroll
    for (int nt = 0; nt < 4; ++nt) {
        float m = accS[0][nt][0];
        #pragma unroll
        for (int mt = 0; mt < 4; ++mt)
            #pragma unroll
            for (int r = 0; r < 4; ++r) m = fmaxf(m, accS[mt][nt][r]);
        m = fmaxf(m, __shfl_xor(m, 16, 64));
        m = fmaxf(m, __shfl_xor(m, 32, 64));
        float s = 0.f;
        #pragma unroll
        for (int mt = 0; mt < 4; ++mt)
            #pragma unroll
            for (int r = 0; r < 4; ++r) {
                float e = exp2f(accS[mt][nt][r] - m);
                accS[mt][nt][r] = e;
                s += e;
            }
        s += __shfl_xor(s, 16, 64);
        s += __shfl_xor(s, 32, 64);
        rinv[nt] = 1.0f / s;
    }

    // P[q][kk] bf16 overwrites qk buffer (q/k dead; same-wave DS ordering is safe)
    #pragma unroll
    for (int mt = 0; mt < 4; ++mt)
        #pragma unroll
        for (int nt = 0; nt < 4; ++nt) {
            u32x2 wv;
            wv.x = pkbf(accS[mt][nt][0], accS[mt][nt][1]);
            wv.y = pkbf(accS[mt][nt][2], accS[mt][nt][3]);
            *(u32x2*)&qk[sw64(16 * nt + c, 16 * mt + 4 * g)] = wv;
        }

    // PV: out_h^T[ch][tok] = V^T . P^T
    f32x4 accO[2][4];
    #pragma unroll
    for (int mD = 0; mD < 2; ++mD)
        #pragma unroll
        for (int nt = 0; nt < 4; ++nt) { f32x4 z = {0.f, 0.f, 0.f, 0.f}; accO[mD][nt] = z; }
    #pragma unroll
    for (int kt = 0; kt < 2; ++kt) {
        bf16x8 va[2];
        #pragma unroll
        for (int mD = 0; mD < 2; ++mD)
            va[mD] = *(const bf16x8*)&vT[sw64(16 * mD + c, 32 * kt + 8 * g)];
        #pragma unroll
        for (int nt = 0; nt < 4; ++nt) {
            bf16x8 pb = *(const bf16x8*)&qk[sw64(16 * nt + c, 32 * kt + 8 * g)];
            #pragma unroll
            for (int mD = 0; mD < 2; ++mD)
                accO[mD][nt] = __builtin_amdgcn_mfma_f32_16x16x32_bf16(va[mD], pb, accO[mD][nt], 0, 0, 0);
        }
    }
    __syncthreads();   // all wave-local reads done -> smem[0..8191] reusable for hc

    // head output (rescaled by 1/sum) -> hc[tok][chan] in smem[0..8191]
    #pragma unroll
    for (int mD = 0; mD < 2; ++mD)
        #pragma unroll
        for (int nt = 0; nt < 4; ++nt) {
            float riv = rinv[nt];
            u32x2 wv;
            wv.x = pkbf(accO[mD][nt][0] * riv, accO[mD][nt][1] * riv);
            wv.y = pkbf(accO[mD][nt][2] * riv, accO[mD][nt][3] * riv);
            *(u32x2*)&Xs[sw128(16 * nt + c, 32 * h + 16 * mD + 4 * g)] = wv;
        }
    __syncthreads();

    // ---- phase C (R1-proven store path): D[tok][och], scalar dword stores.
    //      Consecutive lanes -> consecutive addresses; WRITE_SIZE == output. ----
    bf16x8 ha[4][4];
    #pragma unroll
    for (int mt = 0; mt < 4; ++mt)
        #pragma unroll
        for (int kt = 0; kt < 4; ++kt)
            ha[mt][kt] = *(const bf16x8*)&Xs[sw128(16 * mt + c, 32 * kt + 8 * g)];
    const u16* Wo_ = Wbf + 49152;
    float* ob = out + (size_t)b * 8192;
    #pragma unroll
    for (int j = 0; j < 2; ++j) {
        int OT = 2 * wid + j;
        float bocol = bo[16 * OT + c];
        f32x4 acc[4];
        #pragma unroll
        for (int mt = 0; mt < 4; ++mt) { f32x4 t = {bocol, bocol, bocol, bocol}; acc[mt] = t; }
        const u16* W = Wo_ + (16 * OT + c) * 128;
        #pragma unroll
        for (int kt = 0; kt < 4; ++kt) {
            bf16x8 wf = *(const bf16x8*)(W + 32 * kt + 8 * g);
            #pragma unroll
            for (int mt = 0; mt < 4; ++mt)
                acc[mt] = __builtin_amdgcn_mfma_f32_16x16x32_bf16(ha[mt][kt], wf, acc[mt], 0, 0, 0);
        }
        #pragma unroll
        for (int mt = 0; mt < 4; ++mt)
            #pragma unroll
            for (int r = 0; r < 4; ++r)
                ob[(16 * mt + 4 * g + r) * 128 + 16 * OT + c] = acc[mt][r];
    }
}

extern "C" void kernel_launch(void* const* d_in, const int* in_sizes, int n_in,
                              void* d_out, int out_size, void* d_ws, size_t ws_size,
                              hipStream_t stream)
{
    const float* query      = (const float*)d_in[0];
    const float* Wq         = (const float*)d_in[1];
    const float* bq         = (const float*)d_in[2];
    const float* Wk         = (const float*)d_in[3];
    const float* bk         = (const float*)d_in[4];
    const float* Wv         = (const float*)d_in[5];
    const float* bv         = (const float*)d_in[6];
    const float* Wo         = (const float*)d_in[7];
    const float* bo         = (const float*)d_in[8];
    const float* bias_table = (const float*)d_in[9];
    const int*   rel_index  = (const int*)d_in[10];

    u16*   wsW = (u16*)d_ws;                          // 4 x 32 KB bf16 weights
    float* wsB = (float*)((char*)d_ws + 131072);      // bias, MFMA-C-init layout, 64 KB

    prep_kernel<<<dim3(64), dim3(256), 0, stream>>>(Wq, Wk, Wv, Wo, bias_table, rel_index, wsW, wsB);
    wattn_kernel<<<dim3(4096), dim3(256), 0, stream>>>(query, bq, bk, bv, bo, wsW, wsB, (float*)d_out);
}